// Round 10
// baseline (1028.829 us; speedup 1.0000x reference)
//
#include <hip/hip_runtime.h>
#include <math.h>

// Problem constants
#define NSEQ 4
#define BATCH 256
#define T 64
#define FIN 32
#define S 512
#define KTOT 544     // FIN + S unified k-dimension

// R10: STRUCTURAL change. R5-R9 proved the ~320us floor is protocol-
// invariant: with 4 col-slices every WG needs all 512 h-cols every step ->
// the self-recurrence crosses MALL every step. New decomposition:
//   4 lanes x 16 groups x 2 slices = 128 WGs; each WG = 16 rows x 256 cols.
//   * own 256 h-cols live in h_lds (LDS) across steps -> half the
//     self-recurrence never leaves the CU.
//   * ring exchange = sibling slice's 256 cols + prev-lane p (full 512).
//   * each wave owns 2 col-tiles: B-frags 2x136=272 VGPR, 102 MFMA/step
//     (two independent accumulator chains).
// Protocol = R7 skeleton (proven): per-WG canary dword/slot published by
// tid0 after [stores -> vmcnt(0) -> barrier]; poll4 clause (canary lines +
// stamp lines); read-stamps published at the stage barrier; loose reuse
// guards (sibling >= t-2, consumer >= t-3); poison-keyed FLAG_MAGIC init;
// ALL traffic sc0 sc1 (MALL).
#define NT 512
#define NWG 128
#define RPG 16
#define SW 256       // cols per slice-WG
#define DEPTH 4
#define NKT 17       // K-tiles of 32 (544/32)
#define HLS 260      // h_lds row stride (256 + 4 pad)

// ws float offsets (content is POISON at launch - never read before init)
#define RING_SZ  (4ull * DEPTH * BATCH * S)        // 8 MB state ring
#define OUTP_OFF RING_SZ                            // [gid][sl][16] partials
#define CTL_OFF  (RING_SZ + 16384ull)               // ctl + canary area

#define FLAG_MAGIC 0x13572468u

#define AS 552   // A-LDS row stride in bf16 elems (544 + 8 pad)

typedef __attribute__((ext_vector_type(8))) short short8;      // 8 bf16
typedef __attribute__((ext_vector_type(4))) float f32x4;       // MFMA C/D
typedef __attribute__((ext_vector_type(4))) unsigned u32x4;    // asm 4-dword

// ---- split-bf16: value = hi (truncated bf16) + lo (bf16 of residual) ------
__device__ __forceinline__ unsigned short bf_hi(float f) {
  return (unsigned short)(__float_as_uint(f) >> 16);
}
__device__ __forceinline__ float bf_hi_f(float f) {
  return __uint_as_float(__float_as_uint(f) & 0xFFFF0000u);
}

// ---- MALL (system scope) coherent I/O: sc0 sc1 everywhere -----------------
__device__ __forceinline__ void cstoreu_glb(unsigned* p, unsigned v) {
  asm volatile("global_store_dword %0, %1, off sc0 sc1" :: "v"(p), "v"(v) : "memory");
}
__device__ __forceinline__ u32x4 cld4_glb(const unsigned* p) {
  u32x4 v;
  asm volatile("global_load_dwordx4 %0, %1, off sc0 sc1\n\ts_waitcnt vmcnt(0)"
               : "=v"(v) : "v"(p) : "memory");
  return v;
}
__device__ __forceinline__ void cstore1(float* p, float v) {
  asm volatile("global_store_dword %0, %1, off sc0 sc1" :: "v"(p), "v"(v) : "memory");
}
__device__ __forceinline__ float cload1(const float* p) {
  float v;
  asm volatile("global_load_dword %0, %1, off sc0 sc1\n\ts_waitcnt vmcnt(0)"
               : "=v"(v) : "v"(p) : "memory");
  return v;
}
// poll clause: 4 x 16B control lines, one vmcnt
__device__ __forceinline__ void poll4(u32x4* a, u32x4* b, u32x4* c, u32x4* d,
                                      const unsigned* pa, const unsigned* pb,
                                      const unsigned* pc, const unsigned* pd) {
  asm volatile(
      "global_load_dwordx4 %0, %4, off sc0 sc1\n\t"
      "global_load_dwordx4 %1, %5, off sc0 sc1\n\t"
      "global_load_dwordx4 %2, %6, off sc0 sc1\n\t"
      "global_load_dwordx4 %3, %7, off sc0 sc1\n\t"
      "s_waitcnt vmcnt(0)"
      : "=&v"(*a), "=&v"(*b), "=&v"(*c), "=&v"(*d)
      : "v"(pa), "v"(pb), "v"(pc), "v"(pd) : "memory");
}
// 2 sibling-h blocks (512B apart) + 4 p blocks, one vmcnt
__device__ __forceinline__ void ld_s2p4(float4* s, float4* p,
                                        const float* ps, const float* pp) {
  asm volatile(
      "global_load_dwordx4 %0, %6, off sc0 sc1\n\t"
      "global_load_dwordx4 %1, %6, off offset:512 sc0 sc1\n\t"
      "global_load_dwordx4 %2, %7, off sc0 sc1\n\t"
      "global_load_dwordx4 %3, %7, off offset:512 sc0 sc1\n\t"
      "global_load_dwordx4 %4, %7, off offset:1024 sc0 sc1\n\t"
      "global_load_dwordx4 %5, %7, off offset:1536 sc0 sc1\n\t"
      "s_waitcnt vmcnt(0)"
      : "=&v"(s[0]), "=&v"(s[1]),
        "=&v"(p[0]), "=&v"(p[1]), "=&v"(p[2]), "=&v"(p[3])
      : "v"(ps), "v"(pp) : "memory");
}
__device__ __forceinline__ void ld_s2(float4* s, const float* ps) {
  asm volatile(
      "global_load_dwordx4 %0, %2, off sc0 sc1\n\t"
      "global_load_dwordx4 %1, %2, off offset:512 sc0 sc1\n\t"
      "s_waitcnt vmcnt(0)"
      : "=&v"(s[0]), "=&v"(s[1]) : "v"(ps) : "memory");
}
__device__ __forceinline__ void cload_row(float4* d, const float* p) {
  asm volatile(
      "global_load_dwordx4 %0, %4, off sc0 sc1\n\t"
      "global_load_dwordx4 %1, %4, off offset:512 sc0 sc1\n\t"
      "global_load_dwordx4 %2, %4, off offset:1024 sc0 sc1\n\t"
      "global_load_dwordx4 %3, %4, off offset:1536 sc0 sc1\n\t"
      "s_waitcnt vmcnt(0)"
      : "=&v"(d[0]), "=&v"(d[1]), "=&v"(d[2]), "=&v"(d[3])
      : "v"(p) : "memory");
}

// ctl layout (dwords):
//   ctl + gid*64 + [0..1]      : per-slice read-stamps (one 128B line)
//   ctl + gid*64 + 32 + [0..1] : per-slice init flags (next 128B line)
//   ctl + 8192 + ((lane*4+slot)*16+grp)*32 + [0..1] : per-slice canaries

extern "C" __global__ void __launch_bounds__(NT, 1)
rnn_mfma(const float* __restrict__ x,      // [4][256][64][32]
         const float* __restrict__ Wcell,  // [4][544][512]
         const float* __restrict__ bcell,  // [4][512]
         const float* __restrict__ Wcomb,  // [3][1024]
         const float* __restrict__ bcomb,  // [3]
         const float* __restrict__ Wout,   // [512]
         float* __restrict__ out,          // [1024] = [lane][batch]
         float* __restrict__ ws)
{
  // mapping: b&7 -> XCD heuristic; the 8 WGs of a grp share b&7.
  const int b    = blockIdx.x;        // 0..127
  const int o    = b >> 3;            // 0..15
  const int hi   = o >> 3;            // 0..1
  const int lane = (o >> 1) & 3;
  const int sl   = o & 1;
  const int grp  = (b & 7) + 8 * hi;  // 0..15
  const int gid  = lane * 16 + grp;
  const int r0 = grp * RPG, sb = sl * SW;
  const int tid = threadIdx.x;

  __shared__ __align__(16) unsigned short A1[RPG * AS];  // 17.3 KB hi [x|hc]
  __shared__ __align__(16) unsigned short A2[RPG * AS];  // 17.3 KB lo
  __shared__ __align__(16) float h_lds[RPG * HLS];       // 16.6 KB own h half
  __shared__ float wg_lds[2 * S];                        //  4.0 KB gate weights
  __shared__ float obuf[128];
  __shared__ float fbuf[16];

  float* ring = ws;
  unsigned* ctl      = (unsigned*)(ws + CTL_OFF);
  unsigned* st_own   = ctl + gid * 64;
  unsigned* st_cons  = ctl + (gid + 16) * 64;        // valid iff lane<3
  unsigned* flg_own  = st_own + 32;
  unsigned* flg_prod = ctl + (gid - 16) * 64 + 32;   // valid iff lane>0
  unsigned* flg_cons = st_cons + 32;
  unsigned* can = ctl + 8192;
  const unsigned* psc = (lane < 3) ? st_cons : st_own;

  // ---- poison-keyed init: zero own stamp + own canary dwords, flag, wait --
  if (tid == 0) {
    cstoreu_glb(st_own + sl, 0u);
    #pragma unroll
    for (int slot = 0; slot < 4; ++slot)
      cstoreu_glb(can + ((lane * 4 + slot) * 16 + grp) * 32 + sl, 0u);
    asm volatile("s_waitcnt vmcnt(0)" ::: "memory");
    cstoreu_glb(flg_own + sl, FLAG_MAGIC);
    for (;;) {
      u32x4 f0 = cld4_glb(flg_own);
      bool ok = (f0[0] == FLAG_MAGIC) && (f0[1] == FLAG_MAGIC);
      if (lane > 0) { u32x4 fp = cld4_glb(flg_prod);
                      ok &= (fp[0] == FLAG_MAGIC) && (fp[1] == FLAG_MAGIC); }
      if (lane < 3) { u32x4 fc = cld4_glb(flg_cons);
                      ok &= (fc[0] == FLAG_MAGIC) && (fc[1] == FLAG_MAGIC); }
      if (ok) break;
      __builtin_amdgcn_s_sleep(2);
    }
  }

  // ---- per-thread constants ----
  const float* Wc = Wcell + (size_t)lane * KTOT * S;
  // wave wt owns col-tiles at sb+wt*32 (tile A) and +16 (tile B).
  //   A-frag: row m = wl&15, k = q*8+j   (q = wl>>4)
  //   C/D:    col  = wl&15, row = q*4+reg
  const int wl = tid & 63, wt = tid >> 6;
  const int bn = wl & 15, q = wl >> 4;
  const int ncolA = sb + wt * 32 + bn;
  const int ncolB = ncolA + 16;
  short8 B1a[NKT], B2a[NKT], B1b[NKT], B2b[NKT];   // 272 VGPRs, static
  #pragma unroll
  for (int kt = 0; kt < NKT; ++kt) {
    short8 b1a, b2a, b1b, b2b;
    #pragma unroll
    for (int j = 0; j < 8; ++j) {
      const float wA = Wc[(size_t)(kt * 32 + q * 8 + j) * S + ncolA];
      const float wB = Wc[(size_t)(kt * 32 + q * 8 + j) * S + ncolB];
      b1a[j] = (short)bf_hi(wA); b2a[j] = (short)bf_hi(wA - bf_hi_f(wA));
      b1b[j] = (short)bf_hi(wB); b2b[j] = (short)bf_hi(wB - bf_hi_f(wB));
    }
    B1a[kt] = b1a; B2a[kt] = b2a; B1b[kt] = b1b; B2b[kt] = b2b;
  }
  const float bcvA = bcell[lane * S + ncolA];
  const float bcvB = bcell[lane * S + ncolB];
  const float wovA = Wout[ncolA];
  const float wovB = Wout[ncolB];
  for (int idx = tid; idx < 2 * S; idx += NT)
    wg_lds[idx] = (lane > 0) ? Wcomb[(size_t)(lane - 1) * 2 * S + idx] : 0.0f;
  const float bg = (lane > 0) ? bcomb[lane - 1] : 0.0f;
  // stage/gate mapping: 32 threads per row, 16 rows; wave w owns rows 2w,2w+1
  const int grow = tid >> 5, gch = tid & 31;
  __syncthreads();   // gates on tid0's flag wait too

  float oaccA[4] = {0.f, 0.f, 0.f, 0.f};
  float oaccB[4] = {0.f, 0.f, 0.f, 0.f};

  for (int t = 0; t < T; ++t) {
    // ---- phase A: x stage (per-wave rows) --------------------------------
    {
      const float f0 = x[(((size_t)lane * BATCH + r0 + grow) * T + t) * FIN + gch];
      A1[grow * AS + gch] = bf_hi(f0);
      A2[grow * AS + gch] = bf_hi(f0 - bf_hi_f(f0));
    }

    // ---- phase B: poll (canaries+guards), single data load, gate, stage --
    {
      const unsigned* hcl = can + ((lane * 4 + ((t - 1) & 3)) * 16 + grp) * 32;
      const unsigned* pcl = (lane > 0)
          ? can + (((lane - 1) * 4 + (t & 3)) * 16 + grp) * 32
          : st_own;
      for (;;) {
        u32x4 hc, pc, so, sc;
        poll4(&hc, &pc, &so, &sc, hcl, pcl, st_own, psc);
        bool ok = true;
        if (t > 0)    ok &= ((int)hc[sl ^ 1] >= t);         // sibling h_{t-1}
        if (lane > 0) ok &= ((int)pc[0] >= t + 1) && ((int)pc[1] >= t + 1);
        if (t >= 4) {
          ok &= ((int)so[sl ^ 1] >= t - 2);                 // sibling reuse
          if (lane < 3) ok &= ((int)sc[0] >= t - 3) && ((int)sc[1] >= t - 3);
        }
        if (ok) break;
        __builtin_amdgcn_s_sleep(1);
      }

      float4 hv[4], pv[4];
      const float* hbase = ring + ((size_t)(lane * DEPTH + ((t - 1) & 3)) * BATCH + r0 + grow) * S;
      const float* pbase = ring + ((size_t)((lane - 1) * DEPTH + (t & 3)) * BATCH + r0 + grow) * S;
      const float* sib = hbase + (sl ^ 1) * SW + gch * 4;
      const float* pp  = pbase + gch * 4;
      if (t > 0) {
        float4 s2[2];
        if (lane > 0) ld_s2p4(s2, pv, sib, pp);
        else          ld_s2(s2, sib);
        const int lb = grow * HLS + gch * 4;
        const float4 own0 = *(const float4*)&h_lds[lb];
        const float4 own1 = *(const float4*)&h_lds[lb + 128];
        if (sl == 0) { hv[0] = own0;  hv[1] = own1;  hv[2] = s2[0]; hv[3] = s2[1]; }
        else         { hv[0] = s2[0]; hv[1] = s2[1]; hv[2] = own0;  hv[3] = own1;  }
      } else {
        #pragma unroll
        for (int j = 0; j < 4; ++j) hv[j] = make_float4(0.f, 0.f, 0.f, 0.f);
        if (lane > 0) cload_row(pv, pp);
      }

      if (lane > 0) {
        float gs = 0.0f;
        #pragma unroll
        for (int j = 0; j < 4; ++j) {
          const float* wh = &wg_lds[j * 128 + gch * 4];
          const float* wp = wh + S;
          gs += hv[j].x * wh[0] + hv[j].y * wh[1] + hv[j].z * wh[2] + hv[j].w * wh[3];
          gs += pv[j].x * wp[0] + pv[j].y * wp[1] + pv[j].z * wp[2] + pv[j].w * wp[3];
        }
        gs += __shfl_xor(gs, 1);  gs += __shfl_xor(gs, 2);  gs += __shfl_xor(gs, 4);
        gs += __shfl_xor(gs, 8);  gs += __shfl_xor(gs, 16);  // 32-lane row halves
        const float w = 1.0f / (1.0f + __expf(-(gs + bg)));
        #pragma unroll
        for (int j = 0; j < 4; ++j) {  // hc = p + w*(h-p)
          hv[j].x = fmaf(w, hv[j].x - pv[j].x, pv[j].x);
          hv[j].y = fmaf(w, hv[j].y - pv[j].y, pv[j].y);
          hv[j].z = fmaf(w, hv[j].z - pv[j].z, pv[j].z);
          hv[j].w = fmaf(w, hv[j].w - pv[j].w, pv[j].w);
        }
      }
      #pragma unroll
      for (int j = 0; j < 4; ++j) {
        ushort4 h4, l4;
        h4.x = bf_hi(hv[j].x); l4.x = bf_hi(hv[j].x - bf_hi_f(hv[j].x));
        h4.y = bf_hi(hv[j].y); l4.y = bf_hi(hv[j].y - bf_hi_f(hv[j].y));
        h4.z = bf_hi(hv[j].z); l4.z = bf_hi(hv[j].z - bf_hi_f(hv[j].z));
        h4.w = bf_hi(hv[j].w); l4.w = bf_hi(hv[j].w - bf_hi_f(hv[j].w));
        const int ai = grow * AS + 32 + j * 128 + gch * 4;
        *(ushort4*)&A1[ai] = h4;
        *(ushort4*)&A2[ai] = l4;
      }
    }
    __syncthreads();   // stage complete; ALL ring reads of step t done
    if (tid == 0) cstoreu_glb(st_own + sl, (unsigned)(t + 1));  // read-stamp

    // ---- phase C: MFMA, two col-tiles (independent chains) ---------------
    f32x4 accA = {0.f, 0.f, 0.f, 0.f}, accB = {0.f, 0.f, 0.f, 0.f};
    {
      const unsigned short* ar1 = &A1[bn * AS + q * 8];
      const unsigned short* ar2 = &A2[bn * AS + q * 8];
      #pragma unroll
      for (int kt = 0; kt < NKT; ++kt) {
        const short8 a1 = *(const short8*)(ar1 + kt * 32);
        const short8 a2 = *(const short8*)(ar2 + kt * 32);
        accA = __builtin_amdgcn_mfma_f32_16x16x32_bf16(a1, B1a[kt], accA, 0, 0, 0);
        accB = __builtin_amdgcn_mfma_f32_16x16x32_bf16(a1, B1b[kt], accB, 0, 0, 0);
        accA = __builtin_amdgcn_mfma_f32_16x16x32_bf16(a1, B2a[kt], accA, 0, 0, 0);
        accB = __builtin_amdgcn_mfma_f32_16x16x32_bf16(a1, B2b[kt], accB, 0, 0, 0);
        accA = __builtin_amdgcn_mfma_f32_16x16x32_bf16(a2, B1a[kt], accA, 0, 0, 0);
        accB = __builtin_amdgcn_mfma_f32_16x16x32_bf16(a2, B1b[kt], accB, 0, 0, 0);
      }
    }

    // ---- epilogue: tanh -> h_lds + ring stores; drain; publish -----------
    {
      float* slotp = ring + ((size_t)(lane * DEPTH + (t & 3)) * BATCH + r0) * S + sb;
      #pragma unroll
      for (int reg = 0; reg < 4; ++reg) {
        const float sA = accA[reg] + bcvA;
        const float aA = fabsf(sA), eA = __expf(2.0f * aA);
        const float tA = copysignf(1.0f - 2.0f / (eA + 1.0f), sA);
        h_lds[(q * 4 + reg) * HLS + wt * 32 + bn] = tA;
        cstore1(slotp + (size_t)(q * 4 + reg) * S + wt * 32 + bn, tA);
        const float sB = accB[reg] + bcvB;
        const float aB = fabsf(sB), eB = __expf(2.0f * aB);
        const float tB = copysignf(1.0f - 2.0f / (eB + 1.0f), sB);
        h_lds[(q * 4 + reg) * HLS + wt * 32 + 16 + bn] = tB;
        cstore1(slotp + (size_t)(q * 4 + reg) * S + wt * 32 + 16 + bn, tB);
        if (t == T - 1) { oaccA[reg] = tA * wovA; oaccB[reg] = tB * wovB; }
      }
    }
    asm volatile("s_waitcnt vmcnt(0)" ::: "memory");  // own stores at MALL
    __syncthreads();  // all waves drained; h_lds complete
    if (tid == 0)
      cstoreu_glb(can + ((lane * 4 + (t & 3)) * 16 + grp) * 32 + sl,
                  (unsigned)(t + 1));
  }

  // ---- output: out[lane*256 + r] = h_T[r] . Wout (2-slice combine) --------
  #pragma unroll
  for (int reg = 0; reg < 4; ++reg) {
    float v = oaccA[reg] + oaccB[reg];
    v += __shfl_xor(v, 1); v += __shfl_xor(v, 2);
    v += __shfl_xor(v, 4); v += __shfl_xor(v, 8);  // sum 16 bn-cols (A+B = 32)
    if (bn == 0) obuf[wt * 16 + q * 4 + reg] = v;
  }
  __syncthreads();
  if (tid < 16) {
    float v = 0.0f;
    #pragma unroll
    for (int w = 0; w < 8; ++w) v += obuf[w * 16 + tid];
    fbuf[tid] = v;
    cstore1(ws + OUTP_OFF + (size_t)((gid * 2 + sl) * 16 + tid), v);
  }
  asm volatile("s_waitcnt vmcnt(0)" ::: "memory");
  __syncthreads();
  if (tid == 0) cstoreu_glb(st_own + sl, (unsigned)(T + 1));
  if (sl == 0) {
    if (tid == 0) {
      for (;;) {
        u32x4 s = cld4_glb(st_own);
        if ((int)s[1] >= T + 1) break;
        __builtin_amdgcn_s_sleep(1);
      }
    }
    __syncthreads();
    if (tid < 16) {
      const float sib = cload1(ws + OUTP_OFF + (size_t)((gid * 2 + 1) * 16 + tid));
      out[lane * BATCH + r0 + tid] = fbuf[tid] + sib;
    }
  }
}

extern "C" void kernel_launch(void* const* d_in, const int* in_sizes, int n_in,
                              void* d_out, int out_size, void* d_ws, size_t ws_size,
                              hipStream_t stream) {
  (void)in_sizes; (void)n_in; (void)out_size; (void)ws_size;
  rnn_mfma<<<dim3(NWG), dim3(NT), 0, stream>>>(
      (const float*)d_in[0],   // inputs
      (const float*)d_in[1],   // W_cell
      (const float*)d_in[2],   // b_cell
      (const float*)d_in[3],   // W_comb
      (const float*)d_in[4],   // b_comb
      (const float*)d_in[5],   // W_out
      (float*)d_out,
      (float*)d_ws);
}

// Round 11
// 355.664 us; speedup vs baseline: 2.8927x; 2.8927x over previous
//
#include <hip/hip_runtime.h>
#include <math.h>

// Problem constants
#define NSEQ 4
#define BATCH 256
#define T 64
#define FIN 32
#define S 512
#define KTOT 544     // FIN + S unified k-dimension

// Pipelined decomposition: 4 lanes concurrent (lane i lags i-1 by 1 step).
// Per lane: 16 groups x 16 rows, 4 slice-WGs x 128 cols. 4*16*4 = 256 WGs.
// NT=512 (8 waves). Wave -> one 16x16 col-tile, 17 K-tiles of
// mfma_f32_16x16x32_bf16, SPLIT-BF16 (hi+lo residual, 3 products).
//
// R11 = REVERT to R7 (best verified: 320us hot), per R10 pre-commitment.
// Session ledger: R5 322 / R6 357 / R7 320 / R8 332 / R9 344 / R10 ~1000us.
// The ~320us floor is structural: 64 serial steps x [cross-WG MALL exchange
// ~2 RT + gate/stage/MFMA ~1.5us + straggler quantization over the 16-WG
// clique]. Protocol-level changes (stamp/tag/canary encoding, poll fusion,
// store coalescing, traffic cuts, barrier decoupling) are all null within
// noise; the structural escape (WG-local recurrence, R10) needs 272+ VGPRs
// per thread at NT=512 (HW cap 256) -> spills to scratch -> 3x regression.
//
// R7: CANARY-IN-BAND handshake. Ring stays plain f32. A separate canary
// array canary[lane][slot][grp][row][slice] carries per-(row,slice) step
// numbers:
//   producer: data stores -> vmcnt(0) -> barrier -> canary = t+1
//             (drain guarantees data visible before canary visible)
//   consumer: ONE fused asm block loads h rows + p rows + h/p canary x4 +
//             own/cons guard stamp lines (12 loads, one vmcnt(0)); accepts
//             when canaries match (h==t, p==t+1) and loose guards hold.
// Guards: own >= t-2 (sibling slot-reuse), cons >= t-3 (consumer reuse).
// Canary values are absolute steps (no aliasing). Canary region zeroed at
// init under the per-slice FLAG_MAGIC protocol (ws is re-poisoned every
// launch). ALL traffic sc0 sc1 (MALL) -- no sc0 dirty-line replay hazard.
#define NT 512
#define NWG 256
#define RPG 16
#define SW 128       // cols per slice-WG
#define DEPTH 4
#define NKT 17       // K-tiles of 32 (544/32)

// ws float offsets (content is POISON at launch - never read before init)
#define RING_SZ  (4ull * DEPTH * BATCH * S)        // 8 MB state ring
#define OUTP_OFF RING_SZ                            // [gid][sl][16] partials
#define CTL_OFF  (RING_SZ + 16384ull)               // ctl + canary area

#define FLAG_MAGIC 0x13572468u

#define AS 552   // A-LDS row stride in bf16 elems (544 + 8 pad)

typedef __attribute__((ext_vector_type(8))) short short8;      // 8 bf16
typedef __attribute__((ext_vector_type(4))) float f32x4;       // MFMA C/D
typedef __attribute__((ext_vector_type(4))) unsigned u32x4;    // asm 4-dword

// ---- split-bf16: value = hi (truncated bf16) + lo (bf16 of residual) ------
__device__ __forceinline__ unsigned short bf_hi(float f) {
  return (unsigned short)(__float_as_uint(f) >> 16);
}
__device__ __forceinline__ float bf_hi_f(float f) {
  return __uint_as_float(__float_as_uint(f) & 0xFFFF0000u);
}
__device__ __forceinline__ unsigned umin4(u32x4 v) {
  unsigned a = v[0] < v[1] ? v[0] : v[1];
  unsigned b = v[2] < v[3] ? v[2] : v[3];
  return a < b ? a : b;
}
__device__ __forceinline__ bool alleq4(u32x4 v, unsigned m) {
  return v[0] == m && v[1] == m && v[2] == m && v[3] == m;
}

// ---- MALL (system scope) coherent I/O: sc0 sc1 everywhere -----------------
__device__ __forceinline__ void cstoreu_glb(unsigned* p, unsigned v) {
  asm volatile("global_store_dword %0, %1, off sc0 sc1" :: "v"(p), "v"(v) : "memory");
}
__device__ __forceinline__ void cstore4_glb(unsigned* p, u32x4 v) {
  asm volatile("global_store_dwordx4 %0, %1, off sc0 sc1" :: "v"(p), "v"(v) : "memory");
}
__device__ __forceinline__ u32x4 cld4_glb(const unsigned* p) {
  u32x4 v;
  asm volatile("global_load_dwordx4 %0, %1, off sc0 sc1\n\ts_waitcnt vmcnt(0)"
               : "=v"(v) : "v"(p) : "memory");
  return v;
}
__device__ __forceinline__ void cstore1(float* p, float v) {
  asm volatile("global_store_dword %0, %1, off sc0 sc1" :: "v"(p), "v"(v) : "memory");
}
__device__ __forceinline__ float cload1(const float* p) {
  float v;
  asm volatile("global_load_dword %0, %1, off sc0 sc1\n\ts_waitcnt vmcnt(0)"
               : "=v"(v) : "v"(p) : "memory");
  return v;
}

// ---- fused consumer loads: data + canaries + guard stamps, ONE vmcnt ------
// lane>0, t>0: h rows + p rows + h-canary + p-canary + own-stamps + cons-stamps
__device__ __forceinline__ void ld_full(float4* h, float4* p, u32x4* hc, u32x4* pc,
                                        u32x4* so, u32x4* sc,
                                        const float* ph, const float* pp,
                                        const unsigned* phc, const unsigned* ppc,
                                        const unsigned* pso, const unsigned* psc) {
  asm volatile(
      "global_load_dwordx4 %0, %12, off sc0 sc1\n\t"
      "global_load_dwordx4 %1, %12, off offset:512 sc0 sc1\n\t"
      "global_load_dwordx4 %2, %12, off offset:1024 sc0 sc1\n\t"
      "global_load_dwordx4 %3, %12, off offset:1536 sc0 sc1\n\t"
      "global_load_dwordx4 %4, %13, off sc0 sc1\n\t"
      "global_load_dwordx4 %5, %13, off offset:512 sc0 sc1\n\t"
      "global_load_dwordx4 %6, %13, off offset:1024 sc0 sc1\n\t"
      "global_load_dwordx4 %7, %13, off offset:1536 sc0 sc1\n\t"
      "global_load_dwordx4 %8, %14, off sc0 sc1\n\t"
      "global_load_dwordx4 %9, %15, off sc0 sc1\n\t"
      "global_load_dwordx4 %10, %16, off sc0 sc1\n\t"
      "global_load_dwordx4 %11, %17, off sc0 sc1\n\t"
      "s_waitcnt vmcnt(0)"
      : "=&v"(h[0]), "=&v"(h[1]), "=&v"(h[2]), "=&v"(h[3]),
        "=&v"(p[0]), "=&v"(p[1]), "=&v"(p[2]), "=&v"(p[3]),
        "=&v"(*hc), "=&v"(*pc), "=&v"(*so), "=&v"(*sc)
      : "v"(ph), "v"(pp), "v"(phc), "v"(ppc), "v"(pso), "v"(psc)
      : "memory");
}
// lane==0, t>0: h rows + h-canary + guard stamps
__device__ __forceinline__ void ld_h(float4* h, u32x4* hc, u32x4* so, u32x4* sc,
                                     const float* ph, const unsigned* phc,
                                     const unsigned* pso, const unsigned* psc) {
  asm volatile(
      "global_load_dwordx4 %0, %7, off sc0 sc1\n\t"
      "global_load_dwordx4 %1, %7, off offset:512 sc0 sc1\n\t"
      "global_load_dwordx4 %2, %7, off offset:1024 sc0 sc1\n\t"
      "global_load_dwordx4 %3, %7, off offset:1536 sc0 sc1\n\t"
      "global_load_dwordx4 %4, %8, off sc0 sc1\n\t"
      "global_load_dwordx4 %5, %9, off sc0 sc1\n\t"
      "global_load_dwordx4 %6, %10, off sc0 sc1\n\t"
      "s_waitcnt vmcnt(0)"
      : "=&v"(h[0]), "=&v"(h[1]), "=&v"(h[2]), "=&v"(h[3]),
        "=&v"(*hc), "=&v"(*so), "=&v"(*sc)
      : "v"(ph), "v"(phc), "v"(pso), "v"(psc)
      : "memory");
}
// lane>0, t==0: p rows + p-canary + guard stamps
__device__ __forceinline__ void ld_p(float4* p, u32x4* pc, u32x4* so, u32x4* sc,
                                     const float* pp, const unsigned* ppc,
                                     const unsigned* pso, const unsigned* psc) {
  asm volatile(
      "global_load_dwordx4 %0, %7, off sc0 sc1\n\t"
      "global_load_dwordx4 %1, %7, off offset:512 sc0 sc1\n\t"
      "global_load_dwordx4 %2, %7, off offset:1024 sc0 sc1\n\t"
      "global_load_dwordx4 %3, %7, off offset:1536 sc0 sc1\n\t"
      "global_load_dwordx4 %4, %8, off sc0 sc1\n\t"
      "global_load_dwordx4 %5, %9, off sc0 sc1\n\t"
      "global_load_dwordx4 %6, %10, off sc0 sc1\n\t"
      "s_waitcnt vmcnt(0)"
      : "=&v"(p[0]), "=&v"(p[1]), "=&v"(p[2]), "=&v"(p[3]),
        "=&v"(*pc), "=&v"(*so), "=&v"(*sc)
      : "v"(pp), "v"(ppc), "v"(pso), "v"(psc)
      : "memory");
}

// ctl layout (dwords, stride 64 per gid; stamps and flags on different
// 128B lines):
//   ctl + gid*64 + [0..3]      : per-slice step stamps (one 128B line)
//   ctl + gid*64 + 32 + [0..3] : per-slice init flags (next 128B line)
//   ctl + 8192                  : canary[lane][slot][grp][row][slice] (64KB)

extern "C" __global__ void __launch_bounds__(NT, 1)
rnn_mfma(const float* __restrict__ x,      // [4][256][64][32]
         const float* __restrict__ Wcell,  // [4][544][512]
         const float* __restrict__ bcell,  // [4][512]
         const float* __restrict__ Wcomb,  // [3][1024]
         const float* __restrict__ bcomb,  // [3]
         const float* __restrict__ Wout,   // [512]
         float* __restrict__ out,          // [1024] = [lane][batch]
         float* __restrict__ ws)
{
  // XCD-grouped block mapping (perf heuristic only; correctness is
  // placement-independent: everything goes through MALL).
  const int b    = blockIdx.x;
  const int o    = b >> 3;
  const int grp  = (b & 7) + 8 * (o >> 4);
  const int sub  = o & 15;
  const int lane = sub >> 2;
  const int sl   = sub & 3;
  const int gid  = lane * 16 + grp;
  const int r0 = grp * RPG, sb = sl * SW;
  const int tid = threadIdx.x;

  __shared__ __align__(16) unsigned short A1[RPG * AS];  // 17.3 KB hi [x|hc]
  __shared__ __align__(16) unsigned short A2[RPG * AS];  // 17.3 KB lo
  __shared__ float wg_lds[2 * S];                        //  4.0 KB gate weights
  __shared__ float obuf[128];
  __shared__ float fbuf[64];

  float* ring = ws;
  unsigned* ctl     = (unsigned*)(ws + CTL_OFF);
  unsigned* st_own  = ctl + gid * 64;
  unsigned* st_cons = ctl + (gid + 16) * 64;   // valid iff lane<3
  unsigned* st_mine = st_own + sl;
  unsigned* flg_own  = st_own + 32;
  unsigned* flg_prod = ctl + (gid - 16) * 64 + 32;  // valid iff lane>0
  unsigned* flg_cons = st_cons + 32;
  unsigned* can = ctl + 8192;                  // canary array base
  const unsigned* psc = (lane < 3) ? st_cons : st_own;

  // ---- init: zero own canary slice + (sl0) stamp line, flag, wait set ----
  if (tid < 64) {
    const int slot = tid >> 4, row = tid & 15;
    cstoreu_glb(can + ((((lane * 4 + slot) * 16 + grp) * 16 + row) * 4 + sl), 0u);
  }
  if (sl == 0 && tid == 0) {
    const u32x4 z = {0u, 0u, 0u, 0u};
    cstore4_glb(st_own, z);
  }
  asm volatile("s_waitcnt vmcnt(0)" ::: "memory");
  __syncthreads();                 // all zero-stores of this WG drained
  if (tid == 0) {
    cstoreu_glb(flg_own + sl, FLAG_MAGIC);
    for (;;) {
      bool ok = alleq4(cld4_glb(flg_own), FLAG_MAGIC);
      if (lane > 0) ok &= alleq4(cld4_glb(flg_prod), FLAG_MAGIC);
      if (lane < 3) ok &= alleq4(cld4_glb(flg_cons), FLAG_MAGIC);
      if (ok) break;
      __builtin_amdgcn_s_sleep(2);
    }
  }

  // ---- per-thread constants ----
  const float* Wc = Wcell + (size_t)lane * KTOT * S;
  // MFMA mapping: wave wt (0..7) owns cols [sb+wt*16, +16); within wave:
  //   A-frag: row m = wl&15, k = q*8+j   (q = wl>>4)
  //   B-frag: col n = wl&15, k = q*8+j
  //   C/D:    col  = wl&15, row = q*4+reg
  const int wl = tid & 63, wt = tid >> 6;
  const int bn = wl & 15, q = wl >> 4;
  const int ncol = sb + wt * 16 + bn;
  short8 B1[NKT], B2[NKT];   // split-bf16 weight frags: 136 regs, static
  #pragma unroll
  for (int kt = 0; kt < NKT; ++kt) {
    short8 b1, b2;
    #pragma unroll
    for (int j = 0; j < 8; ++j) {
      const float w = Wc[(size_t)(kt * 32 + q * 8 + j) * S + ncol];
      b1[j] = (short)bf_hi(w);
      b2[j] = (short)bf_hi(w - bf_hi_f(w));
    }
    B1[kt] = b1; B2[kt] = b2;
  }
  const float bcv = bcell[lane * S + ncol];
  const float wov = Wout[ncol];
  for (int idx = tid; idx < 2 * S; idx += NT)
    wg_lds[idx] = (lane > 0) ? Wcomb[(size_t)(lane - 1) * 2 * S + idx] : 0.0f;
  const float bg = (lane > 0) ? bcomb[lane - 1] : 0.0f;
  // stage/gate mapping: 32 threads per row, 16 rows; wave w owns rows 2w,2w+1
  const int grow = tid >> 5, gch = tid & 31;
  __syncthreads();   // gates on tid0's flag wait too

  float oacc[4] = {0.f, 0.f, 0.f, 0.f};

  for (int t = 0; t < T; ++t) {
    // ---- phase A: x stage (per-wave rows); no handshake here -------------
    {
      const float f0 = x[(((size_t)lane * BATCH + r0 + grow) * T + t) * FIN + gch];
      A1[grow * AS + gch] = bf_hi(f0);
      A2[grow * AS + gch] = bf_hi(f0 - bf_hi_f(f0));
    }

    // ---- phase B: fused canary-validated loads + gate + split-stage ------
    {
      float4 hv[4], pv[4];
      const float* hb = ring + ((size_t)(lane * DEPTH + ((t - 1) & 3)) * BATCH + r0 + grow) * S + gch * 4;
      const float* pb = ring + ((size_t)((lane - 1) * DEPTH + (t & 3)) * BATCH + r0 + grow) * S + gch * 4;
      const unsigned* hce = can + (((lane * 4 + ((t - 1) & 3)) * 16 + grp) * 16 + grow) * 4;
      const unsigned* pce = can + ((((lane - 1) * 4 + (t & 3)) * 16 + grp) * 16 + grow) * 4;
      const unsigned th = (unsigned)t, tp = (unsigned)(t + 1);
      u32x4 hcan, pcan, sown, scon;
      if (t > 0) {
        if (lane > 0) {
          for (;;) {
            ld_full(hv, pv, &hcan, &pcan, &sown, &scon, hb, pb, hce, pce, st_own, psc);
            bool ok = ((int)umin4(sown) >= t - 2) && ((int)umin4(scon) >= t - 3);
            ok &= alleq4(hcan, th) && alleq4(pcan, tp);
            if (ok) break;
            __builtin_amdgcn_s_sleep(1);
          }
        } else {
          for (;;) {
            ld_h(hv, &hcan, &sown, &scon, hb, hce, st_own, psc);
            bool ok = ((int)umin4(sown) >= t - 2) && ((int)umin4(scon) >= t - 3);
            ok &= alleq4(hcan, th);
            if (ok) break;
            __builtin_amdgcn_s_sleep(1);
          }
        }
      } else {
        #pragma unroll
        for (int j = 0; j < 4; ++j) hv[j] = make_float4(0.f, 0.f, 0.f, 0.f);
        if (lane > 0) {
          for (;;) {
            ld_p(pv, &pcan, &sown, &scon, pb, pce, st_own, psc);
            if (alleq4(pcan, tp)) break;
            __builtin_amdgcn_s_sleep(1);
          }
        }
      }

      if (lane > 0) {
        float gs = 0.0f;
        #pragma unroll
        for (int j = 0; j < 4; ++j) {
          const float* wh = &wg_lds[j * 128 + gch * 4];
          const float* wp = wh + S;
          gs += hv[j].x * wh[0] + hv[j].y * wh[1] + hv[j].z * wh[2] + hv[j].w * wh[3];
          gs += pv[j].x * wp[0] + pv[j].y * wp[1] + pv[j].z * wp[2] + pv[j].w * wp[3];
        }
        gs += __shfl_xor(gs, 1);  gs += __shfl_xor(gs, 2);  gs += __shfl_xor(gs, 4);
        gs += __shfl_xor(gs, 8);  gs += __shfl_xor(gs, 16);  // 32-lane row halves
        const float w = 1.0f / (1.0f + __expf(-(gs + bg)));
        #pragma unroll
        for (int j = 0; j < 4; ++j) {  // hc = p + w*(h-p)
          hv[j].x = fmaf(w, hv[j].x - pv[j].x, pv[j].x);
          hv[j].y = fmaf(w, hv[j].y - pv[j].y, pv[j].y);
          hv[j].z = fmaf(w, hv[j].z - pv[j].z, pv[j].z);
          hv[j].w = fmaf(w, hv[j].w - pv[j].w, pv[j].w);
        }
      }
      #pragma unroll
      for (int j = 0; j < 4; ++j) {
        ushort4 h4, l4;
        h4.x = bf_hi(hv[j].x); l4.x = bf_hi(hv[j].x - bf_hi_f(hv[j].x));
        h4.y = bf_hi(hv[j].y); l4.y = bf_hi(hv[j].y - bf_hi_f(hv[j].y));
        h4.z = bf_hi(hv[j].z); l4.z = bf_hi(hv[j].z - bf_hi_f(hv[j].z));
        h4.w = bf_hi(hv[j].w); l4.w = bf_hi(hv[j].w - bf_hi_f(hv[j].w));
        const int ai = grow * AS + 32 + j * 128 + gch * 4;
        *(ushort4*)&A1[ai] = h4;
        *(ushort4*)&A2[ai] = l4;
      }
    }
    __syncthreads();

    // ---- phase C: MFMA 16x16 tile, 17 K-tiles x 3 split products ----------
    f32x4 acc = {0.f, 0.f, 0.f, 0.f};
    {
      const unsigned short* ar1 = &A1[bn * AS + q * 8];
      const unsigned short* ar2 = &A2[bn * AS + q * 8];
      #pragma unroll
      for (int kt = 0; kt < NKT; ++kt) {
        const short8 a1 = *(const short8*)(ar1 + kt * 32);
        const short8 a2 = *(const short8*)(ar2 + kt * 32);
        acc = __builtin_amdgcn_mfma_f32_16x16x32_bf16(a1, B1[kt], acc, 0, 0, 0);
        acc = __builtin_amdgcn_mfma_f32_16x16x32_bf16(a1, B2[kt], acc, 0, 0, 0);
        acc = __builtin_amdgcn_mfma_f32_16x16x32_bf16(a2, B1[kt], acc, 0, 0, 0);
      }
    }

    // ---- epilogue: +bias, tanh, ring store, drain, canary+stamp publish --
    float* slot = ring + ((size_t)(lane * DEPTH + (t & 3)) * BATCH + r0) * S + sb;
    #pragma unroll
    for (int reg = 0; reg < 4; ++reg) {
      const float s2 = acc[reg] + bcv;
      const float aa = fabsf(s2), ee = __expf(2.0f * aa);
      const float tv = copysignf(1.0f - 2.0f / (ee + 1.0f), s2);
      cstore1(slot + (size_t)(q * 4 + reg) * S + wt * 16 + bn, tv);
      if (t == T - 1) oacc[reg] = tv * wov;
    }
    asm volatile("s_waitcnt vmcnt(0)" ::: "memory");  // own stores at MALL
    __syncthreads();  // ALL waves' data drained -> canary may publish
    if (tid < 16)
      cstoreu_glb(can + ((((lane * 4 + (t & 3)) * 16 + grp) * 16 + tid) * 4 + sl),
                  (unsigned)(t + 1));
    else if (tid == 16)
      cstoreu_glb(st_mine, (unsigned)(t + 1));
  }

  // ---- output: out[lane*256 + r] = h_T[r] . Wout --------------------------
  #pragma unroll
  for (int reg = 0; reg < 4; ++reg) {
    float v = oacc[reg];
    v += __shfl_xor(v, 1); v += __shfl_xor(v, 2);
    v += __shfl_xor(v, 4); v += __shfl_xor(v, 8);  // sum 16 cols of the tile
    if (bn == 0) obuf[wt * 16 + q * 4 + reg] = v;
  }
  __syncthreads();
  if (tid < 16) {
    float v = 0.0f;
    #pragma unroll
    for (int w = 0; w < 8; ++w) v += obuf[w * 16 + tid];
    cstore1(ws + OUTP_OFF + (size_t)((gid * 4 + sl) * 16 + tid), v);
  }
  asm volatile("s_waitcnt vmcnt(0)" ::: "memory");
  __syncthreads();
  if (tid == 0) cstoreu_glb(st_mine, (unsigned)(T + 1));
  if (sl == 0) {
    if (tid == 0)
      while (umin4(cld4_glb(st_own)) < (unsigned)(T + 1)) __builtin_amdgcn_s_sleep(1);
    __syncthreads();
    if (tid < 64) {
      const int sli = tid >> 4, r = tid & 15;
      fbuf[tid] = cload1(ws + OUTP_OFF + (size_t)((gid * 4 + sli) * 16 + r));
    }
    __syncthreads();
    if (tid < 16) {
      float s2 = 0.f;
      #pragma unroll
      for (int sli = 0; sli < 4; ++sli) s2 += fbuf[sli * 16 + tid];
      out[lane * BATCH + r0 + tid] = s2;
    }
  }
}

extern "C" void kernel_launch(void* const* d_in, const int* in_sizes, int n_in,
                              void* d_out, int out_size, void* d_ws, size_t ws_size,
                              hipStream_t stream) {
  (void)in_sizes; (void)n_in; (void)out_size; (void)ws_size;
  rnn_mfma<<<dim3(NWG), dim3(NT), 0, stream>>>(
      (const float*)d_in[0],   // inputs
      (const float*)d_in[1],   // W_cell
      (const float*)d_in[2],   // b_cell
      (const float*)d_in[3],   // W_comb
      (const float*)d_in[4],   // b_comb
      (const float*)d_in[5],   // W_out
      (float*)d_out,
      (float*)d_ws);
}